// Round 1
// baseline (106.523 us; speedup 1.0000x reference)
//
#include <hip/hip_runtime.h>

#define NB 256          // threads per block
#define APT 32          // atoms per thread (N = NB*APT = 8192)
#define NTYPE 11
#define CPAD 13         // padded per-thread counter row (13 coprime with 32 banks)

__global__ __launch_bounds__(NB)
void typed_coords_kernel(const float* __restrict__ coords,
                         const int*   __restrict__ types,
                         const int*   __restrict__ num_atoms,
                         float* __restrict__ out,       // B*3N floats
                         float* __restrict__ out_cnt,   // B*NTYPE floats
                         float* __restrict__ out_off,   // B*NTYPE floats
                         int N)
{
    const int b    = blockIdx.x;
    const int tid  = threadIdx.x;
    const int lane = tid & 63;
    const int wave = tid >> 6;

    __shared__ int lds_cnt[NB * CPAD];
    __shared__ int lds_counts[NTYPE];
    __shared__ int lds_off[NTYPE];

    const int na = num_atoms[b];
    const int base_i = tid * APT;

    // ---- load my 32 types into registers (skip fully-invalid tails) ----
    int ty[APT];
    const int* tptr = types + (size_t)b * N + base_i;
    if (base_i < na) {
        #pragma unroll
        for (int k4 = 0; k4 < APT / 4; ++k4) {
            int4 v = *reinterpret_cast<const int4*>(tptr + k4 * 4);
            ty[k4 * 4 + 0] = v.x;
            ty[k4 * 4 + 1] = v.y;
            ty[k4 * 4 + 2] = v.z;
            ty[k4 * 4 + 3] = v.w;
        }
    }

    // ---- per-thread histogram in own LDS row ----
    #pragma unroll
    for (int t = 0; t < CPAD; ++t) lds_cnt[tid * CPAD + t] = 0;
    #pragma unroll
    for (int k = 0; k < APT; ++k) {           // static indices only (no scratch)
        if (base_i + k < na) {
            int t = ty[k];
            lds_cnt[tid * CPAD + t] += 1;
        }
    }
    __syncthreads();

    // ---- per-type exclusive scan across the 256 thread rows ----
    // wave w handles types w, w+4, w+8
    for (int tt = wave; tt < NTYPE; tt += 4) {
        int run = 0;
        #pragma unroll
        for (int s = 0; s < NB / 64; ++s) {
            int idx = (s * 64 + lane) * CPAD + tt;
            int v = lds_cnt[idx];
            int x = v;
            #pragma unroll
            for (int d = 1; d < 64; d <<= 1) {
                int n = __shfl_up(x, d);
                if (lane >= d) x += n;
            }
            lds_cnt[idx] = x - v + run;       // exclusive prefix + running base
            run += __shfl(x, 63);
        }
        lds_counts[tt] = run;
    }
    __syncthreads();

    // ---- type offsets (exclusive cumsum over 11 types) ----
    if (tid == 0) {
        int acc = 0;
        #pragma unroll
        for (int t = 0; t < NTYPE; ++t) { lds_off[t] = acc; acc += lds_counts[t]; }
    }
    __syncthreads();

    if (tid < NTYPE) {
        out_cnt[(size_t)b * NTYPE + tid] = (float)lds_counts[tid];
        out_off[(size_t)b * NTYPE + tid] = (float)lds_off[tid];
    }

    // ---- stable scatter of valid coords ----
    const float* cbase = coords + (size_t)b * 3 * N;
    float*       obase = out    + (size_t)b * 3 * N;
    #pragma unroll
    for (int k = 0; k < APT; ++k) {
        int i = base_i + k;
        if (i < na) {
            int t   = ty[k];
            int idx = tid * CPAD + t;
            int r   = lds_cnt[idx];
            lds_cnt[idx] = r + 1;
            int dst = lds_off[t] + r;
            float x = cbase[i * 3 + 0];
            float y = cbase[i * 3 + 1];
            float z = cbase[i * 3 + 2];
            obase[dst * 3 + 0] = x;
            obase[dst * 3 + 1] = y;
            obase[dst * 3 + 2] = z;
        }
    }

    // ---- zero-fill tail [3*na, 3*N) (disjoint from scatter region) ----
    int f0   = 3 * na;
    int fend = 3 * N;
    int f4   = (f0 + 3) & ~3;                 // align up to float4
    if (f4 > fend) f4 = fend;
    if (tid < f4 - f0) obase[f0 + tid] = 0.0f;
    float4 z4 = make_float4(0.f, 0.f, 0.f, 0.f);
    float4* o4 = reinterpret_cast<float4*>(obase);
    for (int q = f4 / 4 + tid; q < fend / 4; q += NB) {
        o4[q] = z4;
    }
}

extern "C" void kernel_launch(void* const* d_in, const int* in_sizes, int n_in,
                              void* d_out, int out_size, void* d_ws, size_t ws_size,
                              hipStream_t stream) {
    const float* coords = (const float*)d_in[0];
    const int*   types  = (const int*)d_in[1];
    const int*   nums   = (const int*)d_in[2];
    const int B = in_sizes[2];            // num_atoms has B elements
    const int N = in_sizes[1] / B;        // 8192

    float* out     = (float*)d_out;
    float* out_cnt = out + (size_t)B * 3 * N;
    float* out_off = out_cnt + (size_t)B * NTYPE;

    typed_coords_kernel<<<B, NB, 0, stream>>>(coords, types, nums,
                                              out, out_cnt, out_off, N);
}

// Round 2
// 47.570 us; speedup vs baseline: 2.2393x; 2.2393x over previous
//
#include <hip/hip_runtime.h>

#define NB 512          // threads per block (8 waves)
#define APT 16          // atoms per thread (N = NB*APT = 8192)
#define NTYPE 11
#define CPAD 13         // padded per-thread counter row
#define NATOMS 8192

__global__ __launch_bounds__(NB)
void typed_coords_kernel(const float* __restrict__ coords,
                         const int*   __restrict__ types,
                         const int*   __restrict__ num_atoms,
                         float* __restrict__ out,       // B*3N floats
                         float* __restrict__ out_cnt,   // B*NTYPE floats
                         float* __restrict__ out_off)   // B*NTYPE floats
{
    const int b    = blockIdx.x;
    const int tid  = threadIdx.x;
    const int lane = tid & 63;
    const int wave = tid >> 6;

    __shared__ float lds_coords[NATOMS * 3];     // 96 KB staged output tile
    __shared__ int   lds_cnt[NB * CPAD];         // 26.6 KB per-thread counters
    __shared__ int   lds_counts[NTYPE];
    __shared__ int   lds_off[NTYPE];

    const int na     = num_atoms[b];
    const int base_i = tid * APT;

    // ---- load my 16 types into registers (skip fully-invalid tails) ----
    int ty[APT];
    const int* tptr = types + (size_t)b * NATOMS + base_i;
    if (base_i < na) {
        #pragma unroll
        for (int g = 0; g < APT / 4; ++g) {
            int4 v = *reinterpret_cast<const int4*>(tptr + g * 4);
            ty[g * 4 + 0] = v.x;
            ty[g * 4 + 1] = v.y;
            ty[g * 4 + 2] = v.z;
            ty[g * 4 + 3] = v.w;
        }
    }

    // ---- per-thread histogram in own LDS row ----
    #pragma unroll
    for (int t = 0; t < CPAD; ++t) lds_cnt[tid * CPAD + t] = 0;
    if (base_i < na) {
        #pragma unroll
        for (int k = 0; k < APT; ++k) {          // static indices only
            if (base_i + k < na) lds_cnt[tid * CPAD + ty[k]] += 1;
        }
    }
    __syncthreads();

    // ---- per-type exclusive scan across the 512 thread rows ----
    // wave w handles types w, w+8
    for (int tt = wave; tt < NTYPE; tt += NB / 64) {
        int run = 0;
        #pragma unroll
        for (int s = 0; s < NB / 64; ++s) {
            int idx = (s * 64 + lane) * CPAD + tt;
            int v = lds_cnt[idx];
            int x = v;
            #pragma unroll
            for (int d = 1; d < 64; d <<= 1) {
                int n = __shfl_up(x, d);
                if (lane >= d) x += n;
            }
            lds_cnt[idx] = x - v + run;          // exclusive prefix + running base
            run += __shfl(x, 63);
        }
        lds_counts[tt] = run;
    }
    __syncthreads();

    // ---- type offsets (exclusive cumsum over 11 types) ----
    if (tid == 0) {
        int acc = 0;
        #pragma unroll
        for (int t = 0; t < NTYPE; ++t) { lds_off[t] = acc; acc += lds_counts[t]; }
    }
    __syncthreads();

    if (tid < NTYPE) {
        out_cnt[(size_t)b * NTYPE + tid] = (float)lds_counts[tid];
        out_off[(size_t)b * NTYPE + tid] = (float)lds_off[tid];
    }

    // ---- zero the invalid tail of the LDS tile [3*na, 3*N) ----
    for (int i = 3 * na + tid; i < 3 * NATOMS; i += NB) lds_coords[i] = 0.0f;

    // ---- stable scatter of valid coords into LDS ----
    if (base_i < na) {
        const float4* c4 = reinterpret_cast<const float4*>(
            coords + (size_t)b * 3 * NATOMS + (size_t)base_i * 3);   // 192B-aligned
        #pragma unroll
        for (int g = 0; g < APT / 4; ++g) {
            float4 va = c4[g * 3 + 0];
            float4 vb = c4[g * 3 + 1];
            float4 vc = c4[g * 3 + 2];
            float xs[12] = {va.x, va.y, va.z, va.w,
                            vb.x, vb.y, vb.z, vb.w,
                            vc.x, vc.y, vc.z, vc.w};
            #pragma unroll
            for (int j = 0; j < 4; ++j) {        // all xs[] indices compile-time
                int k = g * 4 + j;
                if (base_i + k < na) {
                    int t   = ty[k];
                    int idx = tid * CPAD + t;
                    int r   = lds_cnt[idx];
                    lds_cnt[idx] = r + 1;
                    int dst = lds_off[t] + r;
                    lds_coords[dst * 3 + 0] = xs[j * 3 + 0];
                    lds_coords[dst * 3 + 1] = xs[j * 3 + 1];
                    lds_coords[dst * 3 + 2] = xs[j * 3 + 2];
                }
            }
        }
    }
    __syncthreads();

    // ---- fully-coalesced float4 writeout of the whole tile ----
    float4*       o4 = reinterpret_cast<float4*>(out + (size_t)b * 3 * NATOMS);
    const float4* l4 = reinterpret_cast<const float4*>(lds_coords);
    #pragma unroll
    for (int q = 0; q < (3 * NATOMS / 4) / NB; ++q) {   // 12 iterations
        o4[q * NB + tid] = l4[q * NB + tid];
    }
}

extern "C" void kernel_launch(void* const* d_in, const int* in_sizes, int n_in,
                              void* d_out, int out_size, void* d_ws, size_t ws_size,
                              hipStream_t stream) {
    const float* coords = (const float*)d_in[0];
    const int*   types  = (const int*)d_in[1];
    const int*   nums   = (const int*)d_in[2];
    const int B = in_sizes[2];            // num_atoms has B elements

    float* out     = (float*)d_out;
    float* out_cnt = out + (size_t)B * 3 * NATOMS;
    float* out_off = out_cnt + (size_t)B * NTYPE;

    typed_coords_kernel<<<B, NB, 0, stream>>>(coords, types, nums,
                                              out, out_cnt, out_off);
}